// Round 2
// baseline (728.799 us; speedup 1.0000x reference)
//
#include <hip/hip_runtime.h>
#include <math.h>

#define NFFT  8192
#define L_SEQ 8192
#define NC    256
#define NTH   512

typedef float2 cplx;

__device__ __forceinline__ cplx cmul(cplx a, cplx b){
    return make_float2(fmaf(a.x,b.x,-(a.y*b.y)), fmaf(a.x,b.y,a.y*b.x));
}
__device__ __forceinline__ cplx cadd(cplx a, cplx b){ return make_float2(a.x+b.x,a.y+b.y); }
__device__ __forceinline__ cplx csub(cplx a, cplx b){ return make_float2(a.x-b.x,a.y-b.y); }
// bank swizzle: float2 element e -> slot e ^ ((e>>4)&15); bijective, spreads
// stride-32/stride-2 stage patterns across all 16 bank-pairs per 16-lane group
__device__ __forceinline__ int swz(int e){ return e ^ ((e>>4)&15); }

#define C16f 0.9238795325112867f
#define S16f 0.3826834323650898f
#define RH   0.7071067811865476f
#define PI2F 6.28318530717958647692f

template<bool INV>
__device__ __forceinline__ void radix4(cplx& A0, cplx& A1, cplx& A2, cplx& A3){
    cplx t0=cadd(A0,A2), t1=csub(A0,A2), t2=cadd(A1,A3), t3=csub(A1,A3);
    A0=cadd(t0,t2); A2=csub(t0,t2);
    if(!INV){ A1=make_float2(t1.x+t3.y,t1.y-t3.x); A3=make_float2(t1.x-t3.y,t1.y+t3.x); }
    else    { A1=make_float2(t1.x-t3.y,t1.y+t3.x); A3=make_float2(t1.x+t3.y,t1.y-t3.x); }
}
template<bool INV>
__device__ __forceinline__ cplx twid(cplx v, float re, float im){
    return INV ? cmul(v, make_float2(re,  im)) : cmul(v, make_float2(re, -im));
}
template<bool INV>
__device__ __forceinline__ cplx mulmi(cplx v){
    return INV ? make_float2(-v.y, v.x) : make_float2(v.y, -v.x);
}

template<bool INV>
__device__ __forceinline__ void dft16_tail(cplx b[4][4], cplx v[16]){
    b[1][1]=twid<INV>(b[1][1],C16f,S16f);
    b[1][2]=twid<INV>(b[1][2],RH,RH);
    b[1][3]=twid<INV>(b[1][3],S16f,C16f);
    b[2][1]=twid<INV>(b[2][1],RH,RH);
    b[2][2]=mulmi<INV>(b[2][2]);
    b[2][3]=twid<INV>(b[2][3],-RH,RH);
    b[3][1]=twid<INV>(b[3][1],S16f,C16f);
    b[3][2]=twid<INV>(b[3][2],-RH,RH);
    b[3][3]=twid<INV>(b[3][3],-C16f,-S16f);
    #pragma unroll
    for(int k0=0;k0<4;k0++){
        radix4<INV>(b[0][k0],b[1][k0],b[2][k0],b[3][k0]);
        v[k0]=b[0][k0]; v[k0+4]=b[1][k0]; v[k0+8]=b[2][k0]; v[k0+12]=b[3][k0];
    }
}
template<bool INV>
__device__ __forceinline__ void dft16(cplx v[16]){
    cplx b[4][4];
    #pragma unroll
    for(int n0=0;n0<4;n0++){
        b[n0][0]=v[n0]; b[n0][1]=v[n0+4]; b[n0][2]=v[n0+8]; b[n0][3]=v[n0+12];
        radix4<INV>(b[n0][0],b[n0][1],b[n0][2],b[n0][3]);
    }
    dft16_tail<INV>(b, v);
}
// forward dft16 with v[8..15] implicitly zero (never read)
__device__ __forceinline__ void dft16_half(cplx v[16]){
    cplx b[4][4];
    #pragma unroll
    for(int n0=0;n0<4;n0++){
        cplx a=v[n0], bb=v[n0+4];
        b[n0][0]=cadd(a,bb);
        b[n0][1]=make_float2(a.x+bb.y, a.y-bb.x);
        b[n0][2]=csub(a,bb);
        b[n0][3]=make_float2(a.x-bb.y, a.y+bb.x);
    }
    dft16_tail<false>(b, v);
}
// inverse dft16 producing only v[0..7]
__device__ __forceinline__ void idft16_lo(cplx v[16]){
    cplx b[4][4];
    #pragma unroll
    for(int n0=0;n0<4;n0++){
        b[n0][0]=v[n0]; b[n0][1]=v[n0+4]; b[n0][2]=v[n0+8]; b[n0][3]=v[n0+12];
        radix4<true>(b[n0][0],b[n0][1],b[n0][2],b[n0][3]);
    }
    b[1][1]=twid<true>(b[1][1],C16f,S16f);
    b[1][2]=twid<true>(b[1][2],RH,RH);
    b[1][3]=twid<true>(b[1][3],S16f,C16f);
    b[2][1]=twid<true>(b[2][1],RH,RH);
    b[2][2]=mulmi<true>(b[2][2]);
    b[2][3]=twid<true>(b[2][3],-RH,RH);
    b[3][1]=twid<true>(b[3][1],S16f,C16f);
    b[3][2]=twid<true>(b[3][2],-RH,RH);
    b[3][3]=twid<true>(b[3][3],-C16f,-S16f);
    #pragma unroll
    for(int k0=0;k0<4;k0++){
        cplx a=b[0][k0], bb=b[1][k0], c=b[2][k0], d=b[3][k0];
        cplx t0=cadd(a,c), t1=csub(a,c), t2=cadd(bb,d), t3=csub(bb,d);
        v[k0]   = cadd(t0,t2);
        v[k0+4] = make_float2(t1.x - t3.y, t1.y + t3.x);
    }
}
// v[m] *= exp(i*th1*m): 1 sincos + chained cmuls
__device__ __forceinline__ void stwiddle(cplx v[16], float th1){
    float s,c; __sincosf(th1,&s,&c);
    cplx w=make_float2(c,s), wm=w;
    v[1]=cmul(v[1],wm);
    #pragma unroll
    for(int m=2;m<16;m++){ wm=cmul(wm,w); v[m]=cmul(v[m],wm); }
}

template<bool INV>
__device__ __forceinline__ void stageB(cplx* z, int t){
    const int q=t&31, bb=t>>5, base=512*bb+q;
    cplx v[16];
    #pragma unroll
    for(int m=0;m<16;m++) v[m]=z[swz(base+32*m)];
    if(INV){ stwiddle(v,  (PI2F/512.f)*(float)q); dft16<true>(v); }
    else   { dft16<false>(v); stwiddle(v, -(PI2F/512.f)*(float)q); }
    #pragma unroll
    for(int m=0;m<16;m++) z[swz(base+32*m)]=v[m];
}
// forward: radix-16 (Lc=32) then fused radix-2 (Lc=2) via lane shfl
__device__ __forceinline__ void stageCD_fwd(cplx* z, int t){
    const int q=t&1, bb=t>>1, base=32*bb+q;
    cplx v[16];
    #pragma unroll
    for(int m=0;m<16;m++) v[m]=z[swz(base+2*m)];
    dft16<false>(v);
    stwiddle(v, -(PI2F/32.f)*(float)q);
    const float sg = q ? -1.f : 1.f;
    #pragma unroll
    for(int m=0;m<16;m++){
        float ox=__shfl_xor(v[m].x,1), oy=__shfl_xor(v[m].y,1);
        v[m]=make_float2(fmaf(sg,v[m].x,ox), fmaf(sg,v[m].y,oy));
        z[swz(base+2*m)]=v[m];
    }
}
// inverse: fused radix-2 first, then radix-16 (Lc=32)
__device__ __forceinline__ void stageDC_inv(cplx* z, int t){
    const int q=t&1, bb=t>>1, base=32*bb+q;
    cplx v[16];
    #pragma unroll
    for(int m=0;m<16;m++) v[m]=z[swz(base+2*m)];
    const float sg = q ? -1.f : 1.f;
    #pragma unroll
    for(int m=0;m<16;m++){
        float ox=__shfl_xor(v[m].x,1), oy=__shfl_xor(v[m].y,1);
        v[m]=make_float2(fmaf(sg,v[m].x,ox), fmaf(sg,v[m].y,oy));
    }
    stwiddle(v, (PI2F/32.f)*(float)q);
    dft16<true>(v);
    #pragma unroll
    for(int m=0;m<16;m++) z[swz(base+2*m)]=v[m];
}
// position of frequency f after DIF digit-reversal (radices 16,16,16,2)
__device__ __forceinline__ int posf(int f){
    return 512*(f&15) + 32*((f>>4)&15) + 2*((f>>8)&15) + (f>>12);
}

__global__ __launch_bounds__(NTH, 4)
void fftconv_kernel(const float* __restrict__ x,
                    const float* __restrict__ kern,
                    float* __restrict__ out){
    extern __shared__ cplx z[];   // 8192 cplx = 64 KB
    const int t  = threadIdx.x;
    const int c  = blockIdx.x >> 1;
    const int bh = blockIdx.x & 1;
    const int A  = t & 15, B = t >> 4;

    // ---- kern: smooth(window 7, reflect) + soft-threshold -> LDS natural ----
    {
        const float* kr = kern + (size_t)c * L_SEQ;
        float buf[22];
        #pragma unroll
        for(int j=0;j<22;j++){
            int idx = 16*t + j - 3;
            idx = idx < 0 ? -idx : idx;
            idx = idx >= L_SEQ ? 2*L_SEQ-2-idx : idx;
            buf[j] = kr[idx];
        }
        float v16[16];
        float s = buf[0]+buf[1]+buf[2]+buf[3]+buf[4]+buf[5]+buf[6];
        v16[0]=s;
        #pragma unroll
        for(int j=1;j<16;j++){ s += buf[j+6]-buf[j-1]; v16[j]=s; }
        #pragma unroll
        for(int j=0;j<16;j++){
            float sv=v16[j]*(1.f/7.f);
            float a=fabsf(sv)-0.003f;
            v16[j]= a>0.f ? copysignf(a,sv) : 0.f;
        }
        #pragma unroll
        for(int e=0;e<8;e++) z[swz(8*t+e)] = make_float2(v16[2*e], v16[2*e+1]);
    }
    __syncthreads();
    // kern forward FFT: stage A (half input from LDS), B, C+D
    {
        cplx v[16];
        #pragma unroll
        for(int m=0;m<8;m++) v[m]=z[swz(t+512*m)];
        dft16_half(v);
        stwiddle(v, -(PI2F/8192.f)*(float)t);
        #pragma unroll
        for(int m=0;m<16;m++) z[swz(t+512*m)]=v[m];
    }
    __syncthreads();
    stageB<false>(z,t);
    __syncthreads();
    stageCD_fwd(z,t);
    __syncthreads();

    // ---- extract kern rfft bins into registers (f = 256A + 8B + it) ----
    cplx kA[9], kB[9];
    #pragma unroll
    for(int it=0; it<9; ++it){
        const bool act = (it<8) || (t==0);
        const int f = (it<8) ? (256*A + 8*B + it) : 4096;
        if(act){
            const int g  = (NFFT - f) & (NFFT-1);
            const cplx Zf = z[swz(posf(f))];
            const cplx Zg = z[swz(posf(g))];
            float s,cc; __sincosf((PI2F*0.5f/NFFT)*(float)f,&s,&cc);
            cplx E = make_float2(0.5f*(Zf.x+Zg.x), 0.5f*(Zf.y-Zg.y));
            cplx O = make_float2(0.5f*(Zf.y+Zg.y), -0.5f*(Zf.x-Zg.x));
            kA[it] = cadd(E, cmul(make_float2(cc,-s), O));
            kB[it] = cadd(make_float2(E.x,-E.y), cmul(make_float2(-cc,-s), make_float2(O.x,-O.y)));
        }
    }

    // ---- 4 batch rows ----
    for(int bi=0;bi<4;bi++){
        const int b = bh*4 + bi;
        __syncthreads();          // prior readers of z done
        // forward stage A fused with global read (upper half zero)
        {
            const cplx* xr = (const cplx*)(x + ((size_t)b*NC + c)*L_SEQ);
            cplx v[16];
            #pragma unroll
            for(int m=0;m<8;m++) v[m]=xr[t+512*m];
            dft16_half(v);
            stwiddle(v, -(PI2F/8192.f)*(float)t);
            #pragma unroll
            for(int m=0;m<16;m++) z[swz(t+512*m)]=v[m];
        }
        __syncthreads();
        stageB<false>(z,t);
        __syncthreads();
        stageCD_fwd(z,t);
        __syncthreads();
        // pointwise multiply in digit-reversed positions; (f, N-f) pair per thread
        #pragma unroll
        for(int it=0; it<9; ++it){
            const bool act = (it<8) || (t==0);
            const int f = (it<8) ? (256*A + 8*B + it) : 4096;
            if(act){
                const int g  = (NFFT - f) & (NFFT-1);
                const int pf = posf(f), pg = posf(g);
                const cplx Zf = z[swz(pf)];
                const cplx Zg = z[swz(pg)];
                float s,cc; __sincosf((PI2F*0.5f/NFFT)*(float)f,&s,&cc);
                cplx E = make_float2(0.5f*(Zf.x+Zg.x), 0.5f*(Zf.y-Zg.y));
                cplx O = make_float2(0.5f*(Zf.y+Zg.y), -0.5f*(Zf.x-Zg.x));
                cplx Xf = cadd(E, cmul(make_float2(cc,-s), O));
                cplx Xg = cadd(make_float2(E.x,-E.y), cmul(make_float2(-cc,-s), make_float2(O.x,-O.y)));
                cplx Yf = cmul(Xf, kA[it]);
                cplx Yg = cmul(Xg, kB[it]);
                const float inv_n = 1.0f/NFFT;
                Yf.x*=inv_n; Yf.y*=inv_n; Yg.x*=inv_n; Yg.y*=inv_n;
                cplx P = make_float2(0.5f*(Yf.x+Yg.x), 0.5f*(Yf.y-Yg.y));
                cplx Q = make_float2(0.5f*(Yf.x-Yg.x), 0.5f*(Yf.y+Yg.y));
                z[swz(pf)] = cadd(P, cmul(make_float2(-s,cc),Q));
                if(f!=0){
                    cplx Pg = make_float2(P.x,-P.y);
                    cplx Qg = make_float2(-Q.x,Q.y);
                    z[swz(pg)] = cadd(Pg, cmul(make_float2(-s,-cc),Qg));
                }
            }
        }
        __syncthreads();
        stageDC_inv(z,t);
        __syncthreads();
        stageB<true>(z,t);
        __syncthreads();
        // inverse stage A' fused with global write (only low 8 outputs needed)
        {
            cplx v[16];
            #pragma unroll
            for(int m=0;m<16;m++) v[m]=z[swz(t+512*m)];
            stwiddle(v, (PI2F/8192.f)*(float)t);
            idft16_lo(v);
            cplx* orow = (cplx*)(out + ((size_t)b*NC + c)*L_SEQ);
            #pragma unroll
            for(int m=0;m<8;m++) orow[t+512*m]=v[m];
        }
    }
}

extern "C" void kernel_launch(void* const* d_in, const int* in_sizes, int n_in,
                              void* d_out, int out_size, void* d_ws, size_t ws_size,
                              hipStream_t stream) {
    const float* x    = (const float*)d_in[0];
    const float* kern = (const float*)d_in[1];
    float* out        = (float*)d_out;
    const size_t lds_bytes = (size_t)NFFT * sizeof(cplx);  // 64 KB
    hipLaunchKernelGGL(fftconv_kernel, dim3(NC*2), dim3(NTH), lds_bytes, stream,
                       x, kern, out);
}

// Round 3
// 522.387 us; speedup vs baseline: 1.3951x; 1.3951x over previous
//
#include <hip/hip_runtime.h>
#include <math.h>

#define NFFT  8192
#define L_SEQ 8192
#define NC    256
#define NTH   512

typedef float2 cplx;

__device__ __forceinline__ cplx cmul(cplx a, cplx b){
    return make_float2(fmaf(a.x,b.x,-(a.y*b.y)), fmaf(a.x,b.y,a.y*b.x));
}
__device__ __forceinline__ cplx cadd(cplx a, cplx b){ return make_float2(a.x+b.x,a.y+b.y); }
__device__ __forceinline__ cplx csub(cplx a, cplx b){ return make_float2(a.x-b.x,a.y-b.y); }
// bank swizzle: float2 element e -> slot e ^ ((e>>4)&15); bijective, spreads
// stride-32/stride-2 stage patterns across all 16 bank-pairs per 16-lane group
__device__ __forceinline__ int swz(int e){ return e ^ ((e>>4)&15); }

#define C16f 0.9238795325112867f
#define S16f 0.3826834323650898f
#define RH   0.7071067811865476f
#define PI2F 6.28318530717958647692f

template<bool INV>
__device__ __forceinline__ void radix4(cplx& A0, cplx& A1, cplx& A2, cplx& A3){
    cplx t0=cadd(A0,A2), t1=csub(A0,A2), t2=cadd(A1,A3), t3=csub(A1,A3);
    A0=cadd(t0,t2); A2=csub(t0,t2);
    if(!INV){ A1=make_float2(t1.x+t3.y,t1.y-t3.x); A3=make_float2(t1.x-t3.y,t1.y+t3.x); }
    else    { A1=make_float2(t1.x-t3.y,t1.y+t3.x); A3=make_float2(t1.x+t3.y,t1.y-t3.x); }
}
template<bool INV>
__device__ __forceinline__ cplx twid(cplx v, float re, float im){
    return INV ? cmul(v, make_float2(re,  im)) : cmul(v, make_float2(re, -im));
}
template<bool INV>
__device__ __forceinline__ cplx mulmi(cplx v){
    return INV ? make_float2(-v.y, v.x) : make_float2(v.y, -v.x);
}

template<bool INV>
__device__ __forceinline__ void dft16_tail(cplx b[4][4], cplx v[16]){
    b[1][1]=twid<INV>(b[1][1],C16f,S16f);
    b[1][2]=twid<INV>(b[1][2],RH,RH);
    b[1][3]=twid<INV>(b[1][3],S16f,C16f);
    b[2][1]=twid<INV>(b[2][1],RH,RH);
    b[2][2]=mulmi<INV>(b[2][2]);
    b[2][3]=twid<INV>(b[2][3],-RH,RH);
    b[3][1]=twid<INV>(b[3][1],S16f,C16f);
    b[3][2]=twid<INV>(b[3][2],-RH,RH);
    b[3][3]=twid<INV>(b[3][3],-C16f,-S16f);
    #pragma unroll
    for(int k0=0;k0<4;k0++){
        radix4<INV>(b[0][k0],b[1][k0],b[2][k0],b[3][k0]);
        v[k0]=b[0][k0]; v[k0+4]=b[1][k0]; v[k0+8]=b[2][k0]; v[k0+12]=b[3][k0];
    }
}
template<bool INV>
__device__ __forceinline__ void dft16(cplx v[16]){
    cplx b[4][4];
    #pragma unroll
    for(int n0=0;n0<4;n0++){
        b[n0][0]=v[n0]; b[n0][1]=v[n0+4]; b[n0][2]=v[n0+8]; b[n0][3]=v[n0+12];
        radix4<INV>(b[n0][0],b[n0][1],b[n0][2],b[n0][3]);
    }
    dft16_tail<INV>(b, v);
}
// forward dft16 with v[8..15] implicitly zero (never read)
__device__ __forceinline__ void dft16_half(cplx v[16]){
    cplx b[4][4];
    #pragma unroll
    for(int n0=0;n0<4;n0++){
        cplx a=v[n0], bb=v[n0+4];
        b[n0][0]=cadd(a,bb);
        b[n0][1]=make_float2(a.x+bb.y, a.y-bb.x);
        b[n0][2]=csub(a,bb);
        b[n0][3]=make_float2(a.x-bb.y, a.y+bb.x);
    }
    dft16_tail<false>(b, v);
}
// inverse dft16 producing only v[0..7]
__device__ __forceinline__ void idft16_lo(cplx v[16]){
    cplx b[4][4];
    #pragma unroll
    for(int n0=0;n0<4;n0++){
        b[n0][0]=v[n0]; b[n0][1]=v[n0+4]; b[n0][2]=v[n0+8]; b[n0][3]=v[n0+12];
        radix4<true>(b[n0][0],b[n0][1],b[n0][2],b[n0][3]);
    }
    b[1][1]=twid<true>(b[1][1],C16f,S16f);
    b[1][2]=twid<true>(b[1][2],RH,RH);
    b[1][3]=twid<true>(b[1][3],S16f,C16f);
    b[2][1]=twid<true>(b[2][1],RH,RH);
    b[2][2]=mulmi<true>(b[2][2]);
    b[2][3]=twid<true>(b[2][3],-RH,RH);
    b[3][1]=twid<true>(b[3][1],S16f,C16f);
    b[3][2]=twid<true>(b[3][2],-RH,RH);
    b[3][3]=twid<true>(b[3][3],-C16f,-S16f);
    #pragma unroll
    for(int k0=0;k0<4;k0++){
        cplx a=b[0][k0], bb=b[1][k0], c=b[2][k0], d=b[3][k0];
        cplx t0=cadd(a,c), t1=csub(a,c), t2=cadd(bb,d), t3=csub(bb,d);
        v[k0]   = cadd(t0,t2);
        v[k0+4] = make_float2(t1.x - t3.y, t1.y + t3.x);
    }
}
// v[m] *= exp(i*th1*m): 1 sincos + chained cmuls
__device__ __forceinline__ void stwiddle(cplx v[16], float th1){
    float s,c; __sincosf(th1,&s,&c);
    cplx w=make_float2(c,s), wm=w;
    v[1]=cmul(v[1],wm);
    #pragma unroll
    for(int m=2;m<16;m++){ wm=cmul(wm,w); v[m]=cmul(v[m],wm); }
}

template<bool INV>
__device__ __forceinline__ void stageB(cplx* z, int t){
    const int q=t&31, bb=t>>5, base=512*bb+q;
    cplx v[16];
    #pragma unroll
    for(int m=0;m<16;m++) v[m]=z[swz(base+32*m)];
    if(INV){ stwiddle(v,  (PI2F/512.f)*(float)q); dft16<true>(v); }
    else   { dft16<false>(v); stwiddle(v, -(PI2F/512.f)*(float)q); }
    #pragma unroll
    for(int m=0;m<16;m++) z[swz(base+32*m)]=v[m];
}
// forward: radix-16 (Lc=32) then fused radix-2 (Lc=2) via lane shfl
__device__ __forceinline__ void stageCD_fwd(cplx* z, int t){
    const int q=t&1, bb=t>>1, base=32*bb+q;
    cplx v[16];
    #pragma unroll
    for(int m=0;m<16;m++) v[m]=z[swz(base+2*m)];
    dft16<false>(v);
    stwiddle(v, -(PI2F/32.f)*(float)q);
    const float sg = q ? -1.f : 1.f;
    #pragma unroll
    for(int m=0;m<16;m++){
        float ox=__shfl_xor(v[m].x,1), oy=__shfl_xor(v[m].y,1);
        v[m]=make_float2(fmaf(sg,v[m].x,ox), fmaf(sg,v[m].y,oy));
        z[swz(base+2*m)]=v[m];
    }
}
// inverse: fused radix-2 first, then radix-16 (Lc=32)
__device__ __forceinline__ void stageDC_inv(cplx* z, int t){
    const int q=t&1, bb=t>>1, base=32*bb+q;
    cplx v[16];
    #pragma unroll
    for(int m=0;m<16;m++) v[m]=z[swz(base+2*m)];
    const float sg = q ? -1.f : 1.f;
    #pragma unroll
    for(int m=0;m<16;m++){
        float ox=__shfl_xor(v[m].x,1), oy=__shfl_xor(v[m].y,1);
        v[m]=make_float2(fmaf(sg,v[m].x,ox), fmaf(sg,v[m].y,oy));
    }
    stwiddle(v, (PI2F/32.f)*(float)q);
    dft16<true>(v);
    #pragma unroll
    for(int m=0;m<16;m++) z[swz(base+2*m)]=v[m];
}
// position of frequency f after DIF digit-reversal (radices 16,16,16,2)
__device__ __forceinline__ int posf(int f){
    return 512*(f&15) + 32*((f>>4)&15) + 2*((f>>8)&15) + (f>>12);
}

__global__ __launch_bounds__(NTH)   // no min-waves arg: r2's (512,4) forced VGPR=64 -> 4KB/thread scratch spill
void fftconv_kernel(const float* __restrict__ x,
                    const float* __restrict__ kern,
                    float* __restrict__ out){
    extern __shared__ cplx z[];   // 8192 cplx = 64 KB
    const int t  = threadIdx.x;
    const int c  = blockIdx.x >> 1;
    const int bh = blockIdx.x & 1;
    const int A  = t & 15, B = t >> 4;
    const float inv_n = 1.0f/NFFT;

    // ---- kern: smooth(window 7, reflect) + soft-threshold -> LDS natural ----
    {
        const float* kr = kern + (size_t)c * L_SEQ;
        float buf[22];
        #pragma unroll
        for(int j=0;j<22;j++){
            int idx = 16*t + j - 3;
            idx = idx < 0 ? -idx : idx;
            idx = idx >= L_SEQ ? 2*L_SEQ-2-idx : idx;
            buf[j] = kr[idx];
        }
        float v16[16];
        float s = buf[0]+buf[1]+buf[2]+buf[3]+buf[4]+buf[5]+buf[6];
        v16[0]=s;
        #pragma unroll
        for(int j=1;j<16;j++){ s += buf[j+6]-buf[j-1]; v16[j]=s; }
        #pragma unroll
        for(int j=0;j<16;j++){
            float sv=v16[j]*(1.f/7.f);
            float a=fabsf(sv)-0.003f;
            v16[j]= a>0.f ? copysignf(a,sv) : 0.f;
        }
        #pragma unroll
        for(int e=0;e<8;e++) z[swz(8*t+e)] = make_float2(v16[2*e], v16[2*e+1]);
    }
    __syncthreads();
    // kern forward FFT: stage A (half input from LDS), B, C+D
    {
        cplx v[16];
        #pragma unroll
        for(int m=0;m<8;m++) v[m]=z[swz(t+512*m)];
        dft16_half(v);
        stwiddle(v, -(PI2F/8192.f)*(float)t);
        #pragma unroll
        for(int m=0;m<16;m++) z[swz(t+512*m)]=v[m];
    }
    __syncthreads();
    stageB<false>(z,t);
    __syncthreads();
    stageCD_fwd(z,t);
    __syncthreads();

    // ---- extract kern rfft bins into registers (f = 256A + 8B + it), 1/N folded in ----
    cplx kA[8], kB[8];
    cplx kA8 = make_float2(0.f, 0.f);     // f=4096 bin, t==0 only
    #pragma unroll
    for(int it=0; it<8; ++it){
        const int f = 256*A + 8*B + it;
        const int g = (NFFT - f) & (NFFT-1);
        const cplx Zf = z[swz(posf(f))];
        const cplx Zg = z[swz(posf(g))];
        float s,cc; __sincosf((PI2F*0.5f/NFFT)*(float)f,&s,&cc);
        cplx E = make_float2(0.5f*(Zf.x+Zg.x), 0.5f*(Zf.y-Zg.y));
        cplx O = make_float2(0.5f*(Zf.y+Zg.y), -0.5f*(Zf.x-Zg.x));
        cplx a = cadd(E, cmul(make_float2(cc,-s), O));
        cplx b = cadd(make_float2(E.x,-E.y), cmul(make_float2(-cc,-s), make_float2(O.x,-O.y)));
        kA[it] = make_float2(a.x*inv_n, a.y*inv_n);
        kB[it] = make_float2(b.x*inv_n, b.y*inv_n);
    }
    if(t==0){
        // f=4096: posf=1, W=-i  =>  K = conj(Z[4096])
        const cplx Zf = z[swz(1)];
        kA8 = make_float2(Zf.x*inv_n, -Zf.y*inv_n);
    }

    // ---- 4 batch rows ----
    for(int bi=0;bi<4;bi++){
        const int b = bh*4 + bi;
        __syncthreads();          // prior readers of z done
        // forward stage A fused with global read (upper half zero)
        {
            const cplx* xr = (const cplx*)(x + ((size_t)b*NC + c)*L_SEQ);
            cplx v[16];
            #pragma unroll
            for(int m=0;m<8;m++) v[m]=xr[t+512*m];
            dft16_half(v);
            stwiddle(v, -(PI2F/8192.f)*(float)t);
            #pragma unroll
            for(int m=0;m<16;m++) z[swz(t+512*m)]=v[m];
        }
        __syncthreads();
        stageB<false>(z,t);
        __syncthreads();
        stageCD_fwd(z,t);
        __syncthreads();
        // pointwise multiply in digit-reversed positions; (f, N-f) pair per thread
        #pragma unroll
        for(int it=0; it<8; ++it){
            const int f  = 256*A + 8*B + it;
            const int g  = (NFFT - f) & (NFFT-1);
            const int pf = posf(f), pg = posf(g);
            const cplx Zf = z[swz(pf)];
            const cplx Zg = z[swz(pg)];
            float s,cc; __sincosf((PI2F*0.5f/NFFT)*(float)f,&s,&cc);
            cplx E = make_float2(0.5f*(Zf.x+Zg.x), 0.5f*(Zf.y-Zg.y));
            cplx O = make_float2(0.5f*(Zf.y+Zg.y), -0.5f*(Zf.x-Zg.x));
            cplx Xf = cadd(E, cmul(make_float2(cc,-s), O));
            cplx Xg = cadd(make_float2(E.x,-E.y), cmul(make_float2(-cc,-s), make_float2(O.x,-O.y)));
            cplx Yf = cmul(Xf, kA[it]);
            cplx Yg = cmul(Xg, kB[it]);
            cplx P = make_float2(0.5f*(Yf.x+Yg.x), 0.5f*(Yf.y-Yg.y));
            cplx Q = make_float2(0.5f*(Yf.x-Yg.x), 0.5f*(Yf.y+Yg.y));
            z[swz(pf)] = cadd(P, cmul(make_float2(-s,cc),Q));
            if(f!=0){
                cplx Pg = make_float2(P.x,-P.y);
                cplx Qg = make_float2(-Q.x,Q.y);
                z[swz(pg)] = cadd(Pg, cmul(make_float2(-s,-cc),Qg));
            }
        }
        if(t==0){
            // f=4096 (pos 1): X=conj(Z), Y=X*K, z <- conj(Y)
            const cplx Zf = z[swz(1)];
            const cplx Y  = cmul(make_float2(Zf.x,-Zf.y), kA8);
            z[swz(1)] = make_float2(Y.x, -Y.y);
        }
        __syncthreads();
        stageDC_inv(z,t);
        __syncthreads();
        stageB<true>(z,t);
        __syncthreads();
        // inverse stage A' fused with global write (only low 8 outputs needed)
        {
            cplx v[16];
            #pragma unroll
            for(int m=0;m<16;m++) v[m]=z[swz(t+512*m)];
            stwiddle(v, (PI2F/8192.f)*(float)t);
            idft16_lo(v);
            cplx* orow = (cplx*)(out + ((size_t)b*NC + c)*L_SEQ);
            #pragma unroll
            for(int m=0;m<8;m++) orow[t+512*m]=v[m];
        }
    }
}

extern "C" void kernel_launch(void* const* d_in, const int* in_sizes, int n_in,
                              void* d_out, int out_size, void* d_ws, size_t ws_size,
                              hipStream_t stream) {
    const float* x    = (const float*)d_in[0];
    const float* kern = (const float*)d_in[1];
    float* out        = (float*)d_out;
    const size_t lds_bytes = (size_t)NFFT * sizeof(cplx);  // 64 KB
    hipLaunchKernelGGL(fftconv_kernel, dim3(NC*2), dim3(NTH), lds_bytes, stream,
                       x, kern, out);
}